// Round 1
// baseline (454.131 us; speedup 1.0000x reference)
//
#include <hip/hip_runtime.h>
#include <cstdint>
#include <cstddef>

// Problem constants (B=2, L=2048, D=1024, E=8, F=2048, TOP_K=2)
constexpr int T_TOK = 4096;      // B*L
constexpr int D_DIM = 1024;
constexpr int E_NUM = 8;
constexpr int F_DIM = 2048;
constexpr int C2F   = 4096;      // 2*F
constexpr int NPAIR = T_TOK * 2; // 8192 (token, slot) pairs

#define ALPHA_SW 1.702f
#define LIMIT_SW 9.0f

// ---------------- workspace layout (bytes) ----------------
constexpr size_t OFF_OFFSETS = 0;     // int[9]
constexpr size_t OFF_SEL     = 128;
constexpr size_t OFF_WTS     = OFF_SEL    + (size_t)NPAIR * 4;
constexpr size_t OFF_POSOF   = OFF_WTS    + (size_t)NPAIR * 4;
constexpr size_t OFF_FACT    = 131328;                           // f_act bf16 [8192][2048]
constexpr size_t SZ_FACT     = (size_t)NPAIR * F_DIM * 2;        // 33.55 MB
constexpr size_t OFF_XG      = OFF_FACT + SZ_FACT;               // xg bf16 [8192][1024]
constexpr size_t SZ_XG       = (size_t)NPAIR * D_DIM * 2;        // 16.78 MB
constexpr size_t OFF_WB      = OFF_XG + SZ_XG;                   // w1b bf16 (67.1MB); later w2b(33.5)+y(33.5)
constexpr size_t SZ_W2B      = (size_t)E_NUM * D_DIM * F_DIM * 2;// 33.55 MB
constexpr size_t OFF_Y       = OFF_WB + SZ_W2B;                  // y fp32 [8192][1024], overlays w1b tail

typedef __bf16 bf16x8 __attribute__((ext_vector_type(8)));
typedef float  f32x4  __attribute__((ext_vector_type(4)));

// round-half-up f32->bf16
__device__ __forceinline__ uint16_t bf16h(float f) {
  return (uint16_t)((__float_as_uint(f) + 0x8000u) >> 16);
}
__device__ __forceinline__ uint32_t pack2(float lo, float hi) {
  uint32_t ua = __float_as_uint(lo) + 0x8000u;
  uint32_t ub = __float_as_uint(hi) + 0x8000u;
  return __builtin_amdgcn_perm(ub, ua, 0x07060302); // {ub.hi16, ua.hi16}
}

// async global -> LDS, 16B/lane; dest = wave-uniform base + lane*16
__device__ __forceinline__ void gld_lds16(const uint16_t* g, uint16_t* l) {
  __builtin_amdgcn_global_load_lds(
      (const __attribute__((address_space(1))) unsigned int*)g,
      (__attribute__((address_space(3))) unsigned int*)l,
      16, 0, 0);
}

// fast swiglu (proven R5/R6: absmax unchanged at 0.03125)
__device__ __forceinline__ float swiglu_f(float g, float v) {
  g = fminf(g, LIMIT_SW);
  v = fminf(fmaxf(v, -LIMIT_SW), LIMIT_SW);
  float ex = __expf(-ALPHA_SW * g);
  return g * __builtin_amdgcn_rcpf(1.0f + ex) * (v + 1.0f);
}

// compiler-level memory fence + HW barrier (convergent builtin, asm fences stop
// the scheduler from moving LDS/VMEM ops across the barrier)
__device__ __forceinline__ void barrier_fence() {
  asm volatile("" ::: "memory");
  __builtin_amdgcn_s_barrier();
  asm volatile("" ::: "memory");
}
#define LGKM0()  asm volatile("s_waitcnt lgkmcnt(0)" ::: "memory")
#define VMCNT6() asm volatile("s_waitcnt vmcnt(6)" ::: "memory")

// ---------------- K1: gate + top-2 + softmax (NO atomics) ----------------
__global__ __launch_bounds__(256) void gate_route_kernel(
    const float* __restrict__ x, const float* __restrict__ gate_w,
    int* __restrict__ sel, float* __restrict__ wts) {
  const int t = blockIdx.x;
  const int tid = threadIdx.x;
  const int lane = tid & 63, wv = tid >> 6;

  __shared__ double red[4][E_NUM];

  float4 xv = *(const float4*)&x[(size_t)t * D_DIM + tid * 4];
  const float* gw = gate_w + (size_t)tid * 4 * E_NUM;
  float4 g0a = *(const float4*)(gw + 0),  g0b = *(const float4*)(gw + 4);
  float4 g1a = *(const float4*)(gw + 8),  g1b = *(const float4*)(gw + 12);
  float4 g2a = *(const float4*)(gw + 16), g2b = *(const float4*)(gw + 20);
  float4 g3a = *(const float4*)(gw + 24), g3b = *(const float4*)(gw + 28);

  double acc[E_NUM];
  double x0 = xv.x, x1 = xv.y, x2 = xv.z, x3 = xv.w;
  acc[0] = x0*(double)g0a.x + x1*(double)g1a.x + x2*(double)g2a.x + x3*(double)g3a.x;
  acc[1] = x0*(double)g0a.y + x1*(double)g1a.y + x2*(double)g2a.y + x3*(double)g3a.y;
  acc[2] = x0*(double)g0a.z + x1*(double)g1a.z + x2*(double)g2a.z + x3*(double)g3a.z;
  acc[3] = x0*(double)g0a.w + x1*(double)g1a.w + x2*(double)g2a.w + x3*(double)g3a.w;
  acc[4] = x0*(double)g0b.x + x1*(double)g1b.x + x2*(double)g2b.x + x3*(double)g3b.x;
  acc[5] = x0*(double)g0b.y + x1*(double)g1b.y + x2*(double)g2b.y + x3*(double)g3b.y;
  acc[6] = x0*(double)g0b.z + x1*(double)g1b.z + x2*(double)g2b.z + x3*(double)g3b.z;
  acc[7] = x0*(double)g0b.w + x1*(double)g1b.w + x2*(double)g2b.w + x3*(double)g3b.w;

#pragma unroll
  for (int off = 32; off >= 1; off >>= 1) {
#pragma unroll
    for (int e = 0; e < E_NUM; ++e) acc[e] += __shfl_down(acc[e], off, 64);
  }
  if (lane == 0) {
#pragma unroll
    for (int e = 0; e < E_NUM; ++e) red[wv][e] = acc[e];
  }
  __syncthreads();
  if (tid == 0) {
#pragma unroll
    for (int e = 0; e < E_NUM; ++e)
      acc[e] = red[0][e] + red[1][e] + red[2][e] + red[3][e];
    int b0 = 0;
#pragma unroll
    for (int e = 1; e < E_NUM; ++e)
      if (acc[e] > acc[b0]) b0 = e;
    int b1 = (b0 == 0) ? 1 : 0;
#pragma unroll
    for (int e = 0; e < E_NUM; ++e)
      if (e != b0 && acc[e] > acc[b1] && e != b1) {
        if (e < b1 && acc[e] == acc[b1]) continue;
        if (acc[e] > acc[b1]) b1 = e;
      }
    double p0 = 1.0 / (1.0 + exp(acc[b1] - acc[b0]));
    sel[t * 2 + 0] = b0;
    sel[t * 2 + 1] = b1;
    wts[t * 2 + 0] = (float)p0;
    wts[t * 2 + 1] = (float)(1.0 - p0);
  }
}

// ---------------- K2: deterministic routing scan (single block, no atomics) ----------------
__global__ __launch_bounds__(256) void route_scan_kernel(
    const int* __restrict__ sel, int* __restrict__ pos_of, int* __restrict__ offsets) {
  __shared__ int cnt[256 * E_NUM];   // 8 KB
  __shared__ int tot[E_NUM];
  const int tid = threadIdx.x;

  int4 sv[8];
  const int4* sp = (const int4*)(sel + tid * 32);
#pragma unroll
  for (int j = 0; j < 8; ++j) sv[j] = sp[j];

  int local[E_NUM];
#pragma unroll
  for (int e = 0; e < E_NUM; ++e) local[e] = 0;
#pragma unroll
  for (int j = 0; j < 8; ++j) {
#pragma unroll
    for (int e = 0; e < E_NUM; ++e)
      local[e] += (sv[j].x == e) + (sv[j].y == e) + (sv[j].z == e) + (sv[j].w == e);
  }
#pragma unroll
  for (int e = 0; e < E_NUM; ++e) cnt[tid * E_NUM + e] = local[e];
  __syncthreads();

  if (tid < E_NUM) {
    int s = 0;
    for (int t = 0; t < 256; ++t) {
      int c = cnt[t * E_NUM + tid];
      cnt[t * E_NUM + tid] = s;
      s += c;
    }
    tot[tid] = s;
  }
  __syncthreads();
  if (tid == 0) {
    int s = 0;
    for (int e = 0; e < E_NUM; ++e) {
      int c = tot[e];
      tot[e] = s;
      offsets[e] = s;
      s += c;
    }
    offsets[E_NUM] = s;
  }
  __syncthreads();

#pragma unroll
  for (int e = 0; e < E_NUM; ++e) cnt[tid * E_NUM + e] += tot[e];

#pragma unroll
  for (int j = 0; j < 8; ++j) {
    int p = tid * 32 + j * 4;
    int4 v = sv[j];
    int pos;
    pos = cnt[tid * E_NUM + v.x]++; pos_of[p + 0] = pos;
    pos = cnt[tid * E_NUM + v.y]++; pos_of[p + 1] = pos;
    pos = cnt[tid * E_NUM + v.z]++; pos_of[p + 2] = pos;
    pos = cnt[tid * E_NUM + v.w]++; pos_of[p + 3] = pos;
  }
}

// ---------------- K3: gather x row -> both compacted bf16 copies ----------------
__global__ __launch_bounds__(256) void gather_x_kernel(
    const float* __restrict__ x, const int* __restrict__ pos_of,
    uint16_t* __restrict__ xg) {
  int t = blockIdx.x;
  int d = threadIdx.x * 4;
  float4 v = *(const float4*)&x[(size_t)t * D_DIM + d];
  uint2 o;
  o.x = pack2(v.x, v.y);
  o.y = pack2(v.z, v.w);
  int i0 = pos_of[2 * t], i1 = pos_of[2 * t + 1];
  *(uint2*)&xg[(size_t)i0 * D_DIM + d] = o;
  *(uint2*)&xg[(size_t)i1 * D_DIM + d] = o;
}

// ---------------- K4: w1 cvt + g/v row de-interleave (proven R5) ----------------
__global__ __launch_bounds__(256) void cvt_w1_kernel(
    const float* __restrict__ w1, uint16_t* __restrict__ w1b) {
  int row = blockIdx.x;            // e*4096 + c_out
  int c_out = row & (C2F - 1);
  int e = row >> 12;
  int q = c_out >> 5, s = c_out & 31;
  int c_in = (q << 5) + ((s < 16) ? (s << 1) : (((s - 16) << 1) | 1));
  const float* src = w1 + ((size_t)e * C2F + c_in) * D_DIM + threadIdx.x * 4;
  float4 v = *(const float4*)src;
  uint2 o;
  o.x = pack2(v.x, v.y);
  o.y = pack2(v.z, v.w);
  *(uint2*)&w1b[(size_t)row * D_DIM + threadIdx.x * 4] = o;
}

// ---------------- K5: plain f32 -> bf16 convert (w2) ----------------
__global__ __launch_bounds__(256) void cvt_bf16_kernel(
    const float* __restrict__ src, uint16_t* __restrict__ dst, int n4) {
  int i = blockIdx.x * 256 + threadIdx.x;
  if (i >= n4) return;
  float4 v = ((const float4*)src)[i];
  uint2 o;
  o.x = pack2(v.x, v.y);
  o.y = pack2(v.z, v.w);
  ((uint2*)dst)[i] = o;
}

// ---------------- K6: GEMM1 256x256 8-phase  f_act = swiglu(xg @ w1b^T + b1) ----------------
// Geometry: BM=BN=256, BK=64, 8 waves (2M x 4N), per-wave 128x64 output, acc[8][4].
// LDS 128 KiB dynamic: A [2 dbuf][256][64] bf16 @0, B same @32768 elems.
// Swizzle (unchanged, 0-conflict proven): slot s of row r holds k-chunk s^(r&7).
// Half-tile stream order per K-tile: [B0,B1,A0,A1], staged 7 halves (LEAD) ahead;
// steady-state wait = vmcnt(6) (3 half-tiles in flight) once per K-tile.
// A-frag ds_reads front-loaded into phases 1-3 (mi01 | mi23+mi45 | mi67) so the
// phase-4 stage of (t+2).A0 lands in a region whose reads ended a barrier ago.
// Per-phase lgkmcnt(0) before the post-MFMA barrier = cross-wave read-vs-DMA safety.
__global__ __launch_bounds__(512, 2) void gemm1_kernel(
    const uint16_t* __restrict__ xg, const uint16_t* __restrict__ w1b,
    const float* __restrict__ b1, const int* __restrict__ offsets,
    uint16_t* __restrict__ f_act) {
  const int e = blockIdx.z;
  const int base = offsets[e];
  const int n_e = offsets[e + 1] - base;
  const int row0 = blockIdx.y * 256;
  if (row0 >= n_e) return;
  const int c0 = blockIdx.x * 256;

  extern __shared__ uint16_t smem[];
  uint16_t* const smA = smem;            // [2][256][64]
  uint16_t* const smB = smem + 32768;    // [2][256][64]

  const int tid = threadIdx.x;
  const int lane = tid & 63;
  const int wid = tid >> 6;        // 0..7
  const int wm = wid >> 2;         // 0..1 (row half)
  const int wn = wid & 3;          // 0..3 (64-col slice)

  // ---- staging addresses: wave w stages rows w*8+{0..7} (+j*64, +h*128) ----
  const int srow = lane >> 3;
  const int sch8 = ((lane & 7) ^ srow) * 8;
  const uint16_t* agp[2][2];
  const uint16_t* bgp[2][2];
  uint16_t* alds[2][2][2];  // [dbuf][h][j], wave-uniform LDS base
  uint16_t* blds[2][2][2];
#pragma unroll
  for (int h = 0; h < 2; ++h)
#pragma unroll
    for (int j = 0; j < 2; ++j) {
      int rr = h * 128 + j * 64 + wid * 8 + srow;
      int ar = base + row0 + rr; if (ar > NPAIR - 1) ar = NPAIR - 1;
      agp[h][j] = xg + (size_t)ar * D_DIM + sch8;
      bgp[h][j] = w1b + ((size_t)e * C2F + c0 + rr) * D_DIM + sch8;
#pragma unroll
      for (int d = 0; d < 2; ++d) {
        alds[d][h][j] = smA + d * 16384 + (h * 128 + j * 64 + wid * 8) * 64;
        blds[d][h][j] = smB + d * 16384 + (h * 128 + j * 64 + wid * 8) * 64;
      }
    }

#define STG_A(d, h, kt) { gld_lds16(agp[h][0] + (kt) * 64, alds[d][h][0]); \
                          gld_lds16(agp[h][1] + (kt) * 64, alds[d][h][1]); }
#define STG_B(d, h, kt) { gld_lds16(bgp[h][0] + (kt) * 64, blds[d][h][0]); \
                          gld_lds16(bgp[h][1] + (kt) * 64, blds[d][h][1]); }

  // ---- fragment read pointers ----
  const int r15 = lane & 15;
  const int s0 = (lane >> 4) ^ (lane & 7);
  const uint16_t* Ard0 = smA + (wm * 128 + r15) * 64 + s0 * 8;
  const uint16_t* Ard1 = smA + (wm * 128 + r15) * 64 + (s0 ^ 4) * 8;
  const uint16_t* Brd0 = smB + (wn * 64 + r15) * 64 + s0 * 8;
  const uint16_t* Brd1 = smB + (wn * 64 + r15) * 64 + (s0 ^ 4) * 8;

  f32x4 acc[8][4];
#pragma unroll
  for (int mi = 0; mi < 8; ++mi)
#pragma unroll
    for (int ni = 0; ni < 4; ++ni) acc[mi][ni] = (f32x4){0.f, 0.f, 0.f, 0.f};

  auto rdB = [&](bf16x8 (&bf)[4][2], int d) {
#pragma unroll
    for (int ni = 0; ni < 4; ++ni) {
      bf[ni][0] = *(const bf16x8*)(Brd0 + d * 16384 + ni * 1024);
      bf[ni][1] = *(const bf16x8*)(Brd1 + d * 16384 + ni * 1024);
    }
  };
  auto rdA2 = [&](bf16x8 (&a)[2][2], int d, int mi0) {
#pragma unroll
    for (int i = 0; i < 2; ++i) {
      a[i][0] = *(const bf16x8*)(Ard0 + d * 16384 + (mi0 + i) * 1024);
      a[i][1] = *(const bf16x8*)(Ard1 + d * 16384 + (mi0 + i) * 1024);
    }
  };
  auto mfma8 = [&](bf16x8 (&a)[2][2], bf16x8 (&bf)[4][2], int mi0) {
    __builtin_amdgcn_s_setprio(1);
#pragma unroll
    for (int h = 0; h < 2; ++h)
#pragma unroll
      for (int i = 0; i < 2; ++i)
#pragma unroll
        for (int ni = 0; ni < 4; ++ni)
          acc[mi0 + i][ni] = __builtin_amdgcn_mfma_f32_16x16x32_bf16(
              a[i][h], bf[ni][h], acc[mi0 + i][ni], 0, 0, 0);
    __builtin_amdgcn_s_setprio(0);
  };

  // one K-tile = 4 phases; each phase: {ds_reads | stage half-tile | bar | 16 MFMA | lgkm0 (+vm6) | bar}
#define TILE(d, SG0, SG1, SG2, SG3)                                            \
  {                                                                            \
    bf16x8 bfr[4][2], aP[2][2], aQ[2][2], aR[2][2], aS[2][2];                  \
    rdB(bfr, d); rdA2(aP, d, 0);                                               \
    SG0; barrier_fence(); mfma8(aP, bfr, 0); LGKM0(); barrier_fence();         \
    rdA2(aQ, d, 2); rdA2(aR, d, 4);                                            \
    SG1; barrier_fence(); mfma8(aQ, bfr, 2); LGKM0(); barrier_fence();         \
    rdA2(aS, d, 6);                                                            \
    SG2; barrier_fence(); mfma8(aR, bfr, 4); LGKM0(); barrier_fence();         \
    SG3; barrier_fence(); mfma8(aS, bfr, 6); LGKM0(); VMCNT6(); barrier_fence(); \
  }

  // prologue: stream positions 0..6 = tile0{B0,B1,A0,A1} + tile1{B0,B1,A0}
  STG_B(0, 0, 0); STG_B(0, 1, 0); STG_A(0, 0, 0); STG_A(0, 1, 0);
  STG_B(1, 0, 1); STG_B(1, 1, 1); STG_A(1, 0, 1);
  VMCNT6(); barrier_fence();   // tile0 (oldest 8 loads) landed

  constexpr int NT = D_DIM / 64;   // 16 K-tiles, even
  for (int t = 0; t < NT; t += 2) {
    const int k2 = (t + 2 < NT) ? t + 2 : NT - 1;   // tail: re-stage garbage, never read
    const int k3 = (t + 3 < NT) ? t + 3 : NT - 1;
    TILE(0, STG_A(1, 1, t + 1), STG_B(0, 0, k2), STG_B(0, 1, k2), STG_A(0, 0, k2));
    TILE(1, STG_A(0, 1, k2),    STG_B(1, 0, k3), STG_B(1, 1, k3), STG_A(1, 0, k3));
  }
#undef TILE
#undef STG_A
#undef STG_B

  // epilogue: g/v in same lane (ni even=g, ni odd=v); swiglu; predicated stores
  const float* b1e = b1 + (size_t)e * C2F;
  const int rq = (lane >> 4) * 4;
#pragma unroll
  for (int ji = 0; ji < 2; ++ji) {
    int gbase = c0 + wn * 64 + ji * 32;
    float bg = b1e[gbase + 2 * r15];
    float bv = b1e[gbase + 2 * r15 + 1];
    int fcol = (gbase >> 1) + r15;
#pragma unroll
    for (int mi = 0; mi < 8; ++mi)
#pragma unroll
      for (int r = 0; r < 4; ++r) {
        float g = acc[mi][2 * ji][r] + bg;
        float v = acc[mi][2 * ji + 1][r] + bv;
        float f = swiglu_f(g, v);
        int row_l = wm * 128 + mi * 16 + rq + r;
        if (row0 + row_l < n_e)
          f_act[(size_t)(base + row0 + row_l) * F_DIM + fcol] = bf16h(f);
      }
  }
}

// ---------------- K7: GEMM2  y = f_act @ w2b^T + b2  (unchanged 128x128) ----------------
__global__ __launch_bounds__(256) void gemm2_kernel(
    const uint16_t* __restrict__ f_act, const uint16_t* __restrict__ w2b,
    const float* __restrict__ b2, const int* __restrict__ offsets,
    float* __restrict__ y) {
  const int e = blockIdx.z;
  const int base = offsets[e];
  const int n_e = offsets[e + 1] - base;
  const int row0 = blockIdx.y * 128;
  if (row0 >= n_e) return;
  const int c0 = blockIdx.x * 128;

  __shared__ uint16_t As[128 * 64];
  __shared__ uint16_t Bs[128 * 64];

  const int tid = threadIdx.x;
  const int lane = tid & 63;
  const int wv = tid >> 6;
  const int wm = wv & 1, wn = wv >> 1;

  const int srow = lane >> 3;
  const int schunk = ((lane & 7) ^ srow) * 8;
  const uint16_t* agp[4]; uint16_t* alds[4];
  const uint16_t* bgp[4]; uint16_t* blds[4];
#pragma unroll
  for (int j = 0; j < 4; ++j) {
    int tr = wv * 32 + 8 * j + srow;
    int ag = base + row0 + tr; if (ag > NPAIR - 1) ag = NPAIR - 1;
    agp[j] = f_act + (size_t)ag * F_DIM + schunk;
    alds[j] = &As[(wv * 32 + 8 * j) * 64];
    bgp[j] = w2b + ((size_t)e * D_DIM + c0 + tr) * F_DIM + schunk;
    blds[j] = &Bs[(wv * 32 + 8 * j) * 64];
  }

  f32x4 acc[4][4];
#pragma unroll
  for (int mi = 0; mi < 4; ++mi)
#pragma unroll
    for (int ni = 0; ni < 4; ++ni) acc[mi][ni] = (f32x4){0.f, 0.f, 0.f, 0.f};

  const int r15 = lane & 15;
  const int s0 = (lane >> 4) ^ (lane & 7);
  const uint16_t* Ard0 = &As[(wm * 64 + r15) * 64 + s0 * 8];
  const uint16_t* Ard1 = &As[(wm * 64 + r15) * 64 + (s0 ^ 4) * 8];
  const uint16_t* Brd0 = &Bs[(wn * 64 + r15) * 64 + s0 * 8];
  const uint16_t* Brd1 = &Bs[(wn * 64 + r15) * 64 + (s0 ^ 4) * 8];

#pragma unroll
  for (int kt = 0; kt < F_DIM / 64; ++kt) {
    __syncthreads();
#pragma unroll
    for (int j = 0; j < 4; ++j) gld_lds16(agp[j] + kt * 64, alds[j]);
#pragma unroll
    for (int j = 0; j < 4; ++j) gld_lds16(bgp[j] + kt * 64, blds[j]);
    __syncthreads();

#pragma unroll
    for (int h = 0; h < 2; ++h) {
      const uint16_t* Ard = h ? Ard1 : Ard0;
      const uint16_t* Brd = h ? Brd1 : Brd0;
      bf16x8 af[4], bfv[4];
#pragma unroll
      for (int mi = 0; mi < 4; ++mi) af[mi] = *(const bf16x8*)(Ard + mi * 16 * 64);
#pragma unroll
      for (int ni = 0; ni < 4; ++ni) bfv[ni] = *(const bf16x8*)(Brd + ni * 16 * 64);
#pragma unroll
      for (int mi = 0; mi < 4; ++mi)
#pragma unroll
        for (int ni = 0; ni < 4; ++ni)
          acc[mi][ni] = __builtin_amdgcn_mfma_f32_16x16x32_bf16(af[mi], bfv[ni], acc[mi][ni], 0, 0, 0);
    }
  }

  float bias4[4]; int d4a[4];
#pragma unroll
  for (int ni = 0; ni < 4; ++ni) {
    d4a[ni] = c0 + wn * 64 + ni * 16 + r15;
    bias4[ni] = b2[(size_t)e * D_DIM + d4a[ni]];
  }
  const int rq = (lane >> 4) * 4;
#pragma unroll
  for (int mi = 0; mi < 4; ++mi)
#pragma unroll
    for (int r = 0; r < 4; ++r) {
      int grow = row0 + wm * 64 + mi * 16 + rq + r;
      if (grow >= n_e) continue;
      size_t yb = (size_t)(base + grow) * D_DIM;
#pragma unroll
      for (int ni = 0; ni < 4; ++ni)
        y[yb + d4a[ni]] = acc[mi][ni][r] + bias4[ni];
    }
}

// ---------------- K8: combine the two expert outputs per token ----------------
__global__ __launch_bounds__(256) void combine_kernel(
    const float* __restrict__ y, const int* __restrict__ pos_of,
    const float* __restrict__ wts, float* __restrict__ out) {
  int t = blockIdx.x;
  int d4 = threadIdx.x * 4;
  int p0 = pos_of[t * 2], p1 = pos_of[t * 2 + 1];
  float w0 = wts[t * 2], w1v = wts[t * 2 + 1];
  float4 a = *(const float4*)&y[(size_t)p0 * D_DIM + d4];
  float4 b = *(const float4*)&y[(size_t)p1 * D_DIM + d4];
  float4 o;
  o.x = w0 * a.x + w1v * b.x;
  o.y = w0 * a.y + w1v * b.y;
  o.z = w0 * a.z + w1v * b.z;
  o.w = w0 * a.w + w1v * b.w;
  *(float4*)&out[(size_t)t * D_DIM + d4] = o;
}

extern "C" void kernel_launch(void* const* d_in, const int* in_sizes, int n_in,
                              void* d_out, int out_size, void* d_ws, size_t ws_size,
                              hipStream_t stream) {
  const float* x      = (const float*)d_in[0];
  const float* gate_w = (const float*)d_in[1];
  const float* w1     = (const float*)d_in[2];
  const float* b1     = (const float*)d_in[3];
  const float* w2     = (const float*)d_in[4];
  const float* b2     = (const float*)d_in[5];
  float* out = (float*)d_out;

  char* ws = (char*)d_ws;
  int*      offsets = (int*)(ws + OFF_OFFSETS);
  int*      sel     = (int*)(ws + OFF_SEL);
  float*    wts     = (float*)(ws + OFF_WTS);
  int*      pos_of  = (int*)(ws + OFF_POSOF);
  uint16_t* f_act   = (uint16_t*)(ws + OFF_FACT);
  uint16_t* xg      = (uint16_t*)(ws + OFF_XG);
  uint16_t* w1b     = (uint16_t*)(ws + OFF_WB);
  uint16_t* w2b     = (uint16_t*)(ws + OFF_WB);   // reuses w1b region after gemm1
  float*    yb      = (float*)(ws + OFF_Y);       // overlays w1b tail

  static bool s_attr_done = false;
  if (!s_attr_done) {
    hipFuncSetAttribute((const void*)gemm1_kernel,
                        hipFuncAttributeMaxDynamicSharedMemorySize, 131072);
    s_attr_done = true;
  }

  cvt_w1_kernel<<<E_NUM * C2F, 256, 0, stream>>>(w1, w1b);
  gate_route_kernel<<<T_TOK, 256, 0, stream>>>(x, gate_w, sel, wts);
  route_scan_kernel<<<1, 256, 0, stream>>>(sel, pos_of, offsets);
  gather_x_kernel<<<T_TOK, 256, 0, stream>>>(x, pos_of, xg);
  gemm1_kernel<<<dim3(C2F / 256, 16, E_NUM), 512, 131072, stream>>>(xg, w1b, b1, offsets, f_act);
  cvt_bf16_kernel<<<(E_NUM * D_DIM * F_DIM / 4) / 256, 256, 0, stream>>>(
      w2, w2b, E_NUM * D_DIM * F_DIM / 4);
  gemm2_kernel<<<dim3(D_DIM / 128, 64, E_NUM), 256, 0, stream>>>(f_act, w2b, b2, offsets, yb);
  combine_kernel<<<T_TOK, 256, 0, stream>>>(yb, pos_of, wts, out);
}

// Round 3
// 434.632 us; speedup vs baseline: 1.0449x; 1.0449x over previous
//
#include <hip/hip_runtime.h>
#include <cstdint>
#include <cstddef>

// Problem constants (B=2, L=2048, D=1024, E=8, F=2048, TOP_K=2)
constexpr int T_TOK = 4096;      // B*L
constexpr int D_DIM = 1024;
constexpr int E_NUM = 8;
constexpr int F_DIM = 2048;
constexpr int C2F   = 4096;      // 2*F
constexpr int NPAIR = T_TOK * 2; // 8192 (token, slot) pairs

#define ALPHA_SW 1.702f
#define LIMIT_SW 9.0f

// ---------------- workspace layout (bytes) ----------------
constexpr size_t OFF_OFFSETS = 0;     // int[9]
constexpr size_t OFF_SEL     = 128;
constexpr size_t OFF_WTS     = OFF_SEL    + (size_t)NPAIR * 4;
constexpr size_t OFF_POSOF   = OFF_WTS    + (size_t)NPAIR * 4;
constexpr size_t OFF_FACT    = 131328;                           // f_act bf16 [8192][2048]
constexpr size_t SZ_FACT     = (size_t)NPAIR * F_DIM * 2;        // 33.55 MB
constexpr size_t OFF_XG      = OFF_FACT + SZ_FACT;               // xg bf16 [8192][1024]
constexpr size_t SZ_XG       = (size_t)NPAIR * D_DIM * 2;        // 16.78 MB
constexpr size_t OFF_WB      = OFF_XG + SZ_XG;                   // w1b bf16 (67.1MB)
constexpr size_t SZ_W1B      = (size_t)E_NUM * C2F * D_DIM * 2;  // 67.11 MB
constexpr size_t SZ_W2B      = (size_t)E_NUM * D_DIM * F_DIM * 2;// 33.55 MB
constexpr size_t OFF_Y       = OFF_WB + SZ_W2B;                  // y fp32 [8192][1024], overlays w1b tail (w1b dead by gemm2)
// fused-cvt path: w2b placed past w1b (needs ws >= ~151.2 MB); fallback reuses OFF_WB.
constexpr size_t OFF_W2B2    = OFF_WB + SZ_W1B;                  // 117.57 MB
constexpr size_t WS_NEED_FUSED = OFF_W2B2 + SZ_W2B;              // 151.13 MB

typedef __bf16 bf16x8 __attribute__((ext_vector_type(8)));
typedef float  f32x4  __attribute__((ext_vector_type(4)));

// round-half-up f32->bf16
__device__ __forceinline__ uint16_t bf16h(float f) {
  return (uint16_t)((__float_as_uint(f) + 0x8000u) >> 16);
}
__device__ __forceinline__ uint32_t pack2(float lo, float hi) {
  uint32_t ua = __float_as_uint(lo) + 0x8000u;
  uint32_t ub = __float_as_uint(hi) + 0x8000u;
  return __builtin_amdgcn_perm(ub, ua, 0x07060302); // {ub.hi16, ua.hi16}
}

// async global -> LDS, 16B/lane; dest = wave-uniform base + lane*16
__device__ __forceinline__ void gld_lds16(const uint16_t* g, uint16_t* l) {
  __builtin_amdgcn_global_load_lds(
      (const __attribute__((address_space(1))) unsigned int*)g,
      (__attribute__((address_space(3))) unsigned int*)l,
      16, 0, 0);
}

// fast swiglu (proven: absmax unchanged at 0.03125)
__device__ __forceinline__ float swiglu_f(float g, float v) {
  g = fminf(g, LIMIT_SW);
  v = fminf(fmaxf(v, -LIMIT_SW), LIMIT_SW);
  float ex = __expf(-ALPHA_SW * g);
  return g * __builtin_amdgcn_rcpf(1.0f + ex) * (v + 1.0f);
}

// ---------------- K1: gate + top-2 + softmax (NO atomics) ----------------
__global__ __launch_bounds__(256) void gate_route_kernel(
    const float* __restrict__ x, const float* __restrict__ gate_w,
    int* __restrict__ sel, float* __restrict__ wts) {
  const int t = blockIdx.x;
  const int tid = threadIdx.x;
  const int lane = tid & 63, wv = tid >> 6;

  __shared__ double red[4][E_NUM];

  float4 xv = *(const float4*)&x[(size_t)t * D_DIM + tid * 4];
  const float* gw = gate_w + (size_t)tid * 4 * E_NUM;
  float4 g0a = *(const float4*)(gw + 0),  g0b = *(const float4*)(gw + 4);
  float4 g1a = *(const float4*)(gw + 8),  g1b = *(const float4*)(gw + 12);
  float4 g2a = *(const float4*)(gw + 16), g2b = *(const float4*)(gw + 20);
  float4 g3a = *(const float4*)(gw + 24), g3b = *(const float4*)(gw + 28);

  double acc[E_NUM];
  double x0 = xv.x, x1 = xv.y, x2 = xv.z, x3 = xv.w;
  acc[0] = x0*(double)g0a.x + x1*(double)g1a.x + x2*(double)g2a.x + x3*(double)g3a.x;
  acc[1] = x0*(double)g0a.y + x1*(double)g1a.y + x2*(double)g2a.y + x3*(double)g3a.y;
  acc[2] = x0*(double)g0a.z + x1*(double)g1a.z + x2*(double)g2a.z + x3*(double)g3a.z;
  acc[3] = x0*(double)g0a.w + x1*(double)g1a.w + x2*(double)g2a.w + x3*(double)g3a.w;
  acc[4] = x0*(double)g0b.x + x1*(double)g1b.x + x2*(double)g2b.x + x3*(double)g3b.x;
  acc[5] = x0*(double)g0b.y + x1*(double)g1b.y + x2*(double)g2b.y + x3*(double)g3b.y;
  acc[6] = x0*(double)g0b.z + x1*(double)g1b.z + x2*(double)g2b.z + x3*(double)g3b.z;
  acc[7] = x0*(double)g0b.w + x1*(double)g1b.w + x2*(double)g2b.w + x3*(double)g3b.w;

#pragma unroll
  for (int off = 32; off >= 1; off >>= 1) {
#pragma unroll
    for (int e = 0; e < E_NUM; ++e) acc[e] += __shfl_down(acc[e], off, 64);
  }
  if (lane == 0) {
#pragma unroll
    for (int e = 0; e < E_NUM; ++e) red[wv][e] = acc[e];
  }
  __syncthreads();
  if (tid == 0) {
#pragma unroll
    for (int e = 0; e < E_NUM; ++e)
      acc[e] = red[0][e] + red[1][e] + red[2][e] + red[3][e];
    int b0 = 0;
#pragma unroll
    for (int e = 1; e < E_NUM; ++e)
      if (acc[e] > acc[b0]) b0 = e;
    int b1 = (b0 == 0) ? 1 : 0;
#pragma unroll
    for (int e = 0; e < E_NUM; ++e)
      if (e != b0 && acc[e] > acc[b1] && e != b1) {
        if (e < b1 && acc[e] == acc[b1]) continue;
        if (acc[e] > acc[b1]) b1 = e;
      }
    double p0 = 1.0 / (1.0 + exp(acc[b1] - acc[b0]));
    sel[t * 2 + 0] = b0;
    sel[t * 2 + 1] = b1;
    wts[t * 2 + 0] = (float)p0;
    wts[t * 2 + 1] = (float)(1.0 - p0);
  }
}

// ---------------- K2: deterministic routing scan (single block, no atomics) ----------------
__global__ __launch_bounds__(256) void route_scan_kernel(
    const int* __restrict__ sel, int* __restrict__ pos_of, int* __restrict__ offsets) {
  __shared__ int cnt[256 * E_NUM];   // 8 KB
  __shared__ int tot[E_NUM];
  const int tid = threadIdx.x;

  int4 sv[8];
  const int4* sp = (const int4*)(sel + tid * 32);
#pragma unroll
  for (int j = 0; j < 8; ++j) sv[j] = sp[j];

  int local[E_NUM];
#pragma unroll
  for (int e = 0; e < E_NUM; ++e) local[e] = 0;
#pragma unroll
  for (int j = 0; j < 8; ++j) {
#pragma unroll
    for (int e = 0; e < E_NUM; ++e)
      local[e] += (sv[j].x == e) + (sv[j].y == e) + (sv[j].z == e) + (sv[j].w == e);
  }
#pragma unroll
  for (int e = 0; e < E_NUM; ++e) cnt[tid * E_NUM + e] = local[e];
  __syncthreads();

  if (tid < E_NUM) {
    int s = 0;
    for (int t = 0; t < 256; ++t) {
      int c = cnt[t * E_NUM + tid];
      cnt[t * E_NUM + tid] = s;
      s += c;
    }
    tot[tid] = s;
  }
  __syncthreads();
  if (tid == 0) {
    int s = 0;
    for (int e = 0; e < E_NUM; ++e) {
      int c = tot[e];
      tot[e] = s;
      offsets[e] = s;
      s += c;
    }
    offsets[E_NUM] = s;
  }
  __syncthreads();

#pragma unroll
  for (int e = 0; e < E_NUM; ++e) cnt[tid * E_NUM + e] += tot[e];

#pragma unroll
  for (int j = 0; j < 8; ++j) {
    int p = tid * 32 + j * 4;
    int4 v = sv[j];
    int pos;
    pos = cnt[tid * E_NUM + v.x]++; pos_of[p + 0] = pos;
    pos = cnt[tid * E_NUM + v.y]++; pos_of[p + 1] = pos;
    pos = cnt[tid * E_NUM + v.z]++; pos_of[p + 2] = pos;
    pos = cnt[tid * E_NUM + v.w]++; pos_of[p + 3] = pos;
  }
}

// ---------------- K3: gather x row -> both compacted bf16 copies ----------------
__global__ __launch_bounds__(256) void gather_x_kernel(
    const float* __restrict__ x, const int* __restrict__ pos_of,
    uint16_t* __restrict__ xg) {
  int t = blockIdx.x;
  int d = threadIdx.x * 4;
  float4 v = *(const float4*)&x[(size_t)t * D_DIM + d];
  uint2 o;
  o.x = pack2(v.x, v.y);
  o.y = pack2(v.z, v.w);
  int i0 = pos_of[2 * t], i1 = pos_of[2 * t + 1];
  *(uint2*)&xg[(size_t)i0 * D_DIM + d] = o;
  *(uint2*)&xg[(size_t)i1 * D_DIM + d] = o;
}

// ---------------- K4: w1 cvt + g/v row de-interleave (proven) ----------------
__global__ __launch_bounds__(256) void cvt_w1_kernel(
    const float* __restrict__ w1, uint16_t* __restrict__ w1b) {
  int row = blockIdx.x;            // e*4096 + c_out
  int c_out = row & (C2F - 1);
  int e = row >> 12;
  int q = c_out >> 5, s = c_out & 31;
  int c_in = (q << 5) + ((s < 16) ? (s << 1) : (((s - 16) << 1) | 1));
  const float* src = w1 + ((size_t)e * C2F + c_in) * D_DIM + threadIdx.x * 4;
  float4 v = *(const float4*)src;
  uint2 o;
  o.x = pack2(v.x, v.y);
  o.y = pack2(v.z, v.w);
  *(uint2*)&w1b[(size_t)row * D_DIM + threadIdx.x * 4] = o;
}

// ---------------- K5: plain f32 -> bf16 convert (w2, fallback path) ----------------
__global__ __launch_bounds__(256) void cvt_bf16_kernel(
    const float* __restrict__ src, uint16_t* __restrict__ dst, int n4) {
  int i = blockIdx.x * 256 + threadIdx.x;
  if (i >= n4) return;
  float4 v = ((const float4*)src)[i];
  uint2 o;
  o.x = pack2(v.x, v.y);
  o.y = pack2(v.z, v.w);
  ((uint2*)dst)[i] = o;
}

// LDS tile: 128 rows x 64 bf16 (BK=64); row = 128B = 8 chunks of 16B.
// Swizzle: slot s of row r holds k-chunk s ^ (r&7) — conflict-free (proven).

// ---------------- K6: GEMM1  f_act = swiglu(xg @ w1b^T + b1) ----------------
// Proven 128x128 structure (106 us). Extra z==E_NUM slice: w2 f32->bf16 cvt
// blocks co-scheduled with the GEMM (hides the cvt pass under gemm1's idle
// HBM bandwidth; gemm1 runs at 17% HBM). Only taken on the fused path.
__global__ __launch_bounds__(256) void gemm1_kernel(
    const uint16_t* __restrict__ xg, const uint16_t* __restrict__ w1b,
    const float* __restrict__ b1, const int* __restrict__ offsets,
    uint16_t* __restrict__ f_act,
    const float* __restrict__ w2, uint16_t* __restrict__ w2b) {
  if (blockIdx.z == E_NUM) {
    // fused w2 conversion: 2048 blocks x 256 threads, 8 float4 each
    const int nthr = 2048 * 256;
    int i = (blockIdx.y * gridDim.x + blockIdx.x) * 256 + threadIdx.x;
    const int n4 = E_NUM * D_DIM * F_DIM / 4;
#pragma unroll
    for (int it = 0; it < 8; ++it, i += nthr) {
      if (i < n4) {
        float4 v = ((const float4*)w2)[i];
        uint2 o;
        o.x = pack2(v.x, v.y);
        o.y = pack2(v.z, v.w);
        ((uint2*)w2b)[i] = o;
      }
    }
    return;
  }

  const int e = blockIdx.z;
  const int base = offsets[e];
  const int n_e = offsets[e + 1] - base;
  const int row0 = blockIdx.y * 128;
  if (row0 >= n_e) return;
  const int c0 = blockIdx.x * 128;

  __shared__ uint16_t As[128 * 64];   // 16 KB
  __shared__ uint16_t Bs[128 * 64];   // 16 KB

  const int tid = threadIdx.x;
  const int lane = tid & 63;
  const int wv = tid >> 6;
  const int wm = wv & 1, wn = wv >> 1;

  const int srow = lane >> 3;
  const int schunk = ((lane & 7) ^ srow) * 8;
  const uint16_t* agp[4]; uint16_t* alds[4];
  const uint16_t* bgp[4]; uint16_t* blds[4];
#pragma unroll
  for (int j = 0; j < 4; ++j) {
    int tr = wv * 32 + 8 * j + srow;
    int ag = base + row0 + tr; if (ag > NPAIR - 1) ag = NPAIR - 1;
    agp[j] = xg + (size_t)ag * D_DIM + schunk;
    alds[j] = &As[(wv * 32 + 8 * j) * 64];
    bgp[j] = w1b + ((size_t)e * C2F + c0 + tr) * D_DIM + schunk;
    blds[j] = &Bs[(wv * 32 + 8 * j) * 64];
  }

  f32x4 acc[4][4];
#pragma unroll
  for (int mi = 0; mi < 4; ++mi)
#pragma unroll
    for (int ni = 0; ni < 4; ++ni) acc[mi][ni] = (f32x4){0.f, 0.f, 0.f, 0.f};

  const int r15 = lane & 15;
  const int s0 = (lane >> 4) ^ (lane & 7);
  const uint16_t* Ard0 = &As[(wm * 64 + r15) * 64 + s0 * 8];
  const uint16_t* Ard1 = &As[(wm * 64 + r15) * 64 + (s0 ^ 4) * 8];
  const uint16_t* Brd0 = &Bs[(wn * 64 + r15) * 64 + s0 * 8];
  const uint16_t* Brd1 = &Bs[(wn * 64 + r15) * 64 + (s0 ^ 4) * 8];

#pragma unroll
  for (int kt = 0; kt < D_DIM / 64; ++kt) {
    __syncthreads();
#pragma unroll
    for (int j = 0; j < 4; ++j) gld_lds16(agp[j] + kt * 64, alds[j]);
#pragma unroll
    for (int j = 0; j < 4; ++j) gld_lds16(bgp[j] + kt * 64, blds[j]);
    __syncthreads();

#pragma unroll
    for (int h = 0; h < 2; ++h) {
      const uint16_t* Ard = h ? Ard1 : Ard0;
      const uint16_t* Brd = h ? Brd1 : Brd0;
      bf16x8 af[4], bfv[4];
#pragma unroll
      for (int mi = 0; mi < 4; ++mi) af[mi] = *(const bf16x8*)(Ard + mi * 16 * 64);
#pragma unroll
      for (int ni = 0; ni < 4; ++ni) bfv[ni] = *(const bf16x8*)(Brd + ni * 16 * 64);
#pragma unroll
      for (int mi = 0; mi < 4; ++mi)
#pragma unroll
        for (int ni = 0; ni < 4; ++ni)
          acc[mi][ni] = __builtin_amdgcn_mfma_f32_16x16x32_bf16(af[mi], bfv[ni], acc[mi][ni], 0, 0, 0);
    }
  }

  // epilogue: g/v in same lane (ni even=g, ni odd=v); 32 swiglu, no shfl (proven)
  const float* b1e = b1 + (size_t)e * C2F;
  const int rq = (lane >> 4) * 4;
#pragma unroll
  for (int ji = 0; ji < 2; ++ji) {
    int gbase = c0 + wn * 64 + ji * 32;
    float bg = b1e[gbase + 2 * r15];
    float bv = b1e[gbase + 2 * r15 + 1];
    int fcol = (gbase >> 1) + r15;
#pragma unroll
    for (int mi = 0; mi < 4; ++mi)
#pragma unroll
      for (int r = 0; r < 4; ++r) {
        float g = acc[mi][2 * ji][r] + bg;
        float v = acc[mi][2 * ji + 1][r] + bv;
        float f = swiglu_f(g, v);
        int row_l = wm * 64 + mi * 16 + rq + r;
        if (row0 + row_l < n_e)
          f_act[(size_t)(base + row0 + row_l) * F_DIM + fcol] = bf16h(f);
      }
  }
}

// ---------------- K7: GEMM2  y = f_act @ w2b^T + b2  (plain stores) ----------------
__global__ __launch_bounds__(256) void gemm2_kernel(
    const uint16_t* __restrict__ f_act, const uint16_t* __restrict__ w2b,
    const float* __restrict__ b2, const int* __restrict__ offsets,
    float* __restrict__ y) {
  const int e = blockIdx.z;
  const int base = offsets[e];
  const int n_e = offsets[e + 1] - base;
  const int row0 = blockIdx.y * 128;
  if (row0 >= n_e) return;
  const int c0 = blockIdx.x * 128;

  __shared__ uint16_t As[128 * 64];
  __shared__ uint16_t Bs[128 * 64];

  const int tid = threadIdx.x;
  const int lane = tid & 63;
  const int wv = tid >> 6;
  const int wm = wv & 1, wn = wv >> 1;

  const int srow = lane >> 3;
  const int schunk = ((lane & 7) ^ srow) * 8;
  const uint16_t* agp[4]; uint16_t* alds[4];
  const uint16_t* bgp[4]; uint16_t* blds[4];
#pragma unroll
  for (int j = 0; j < 4; ++j) {
    int tr = wv * 32 + 8 * j + srow;
    int ag = base + row0 + tr; if (ag > NPAIR - 1) ag = NPAIR - 1;
    agp[j] = f_act + (size_t)ag * F_DIM + schunk;
    alds[j] = &As[(wv * 32 + 8 * j) * 64];
    bgp[j] = w2b + ((size_t)e * D_DIM + c0 + tr) * F_DIM + schunk;
    blds[j] = &Bs[(wv * 32 + 8 * j) * 64];
  }

  f32x4 acc[4][4];
#pragma unroll
  for (int mi = 0; mi < 4; ++mi)
#pragma unroll
    for (int ni = 0; ni < 4; ++ni) acc[mi][ni] = (f32x4){0.f, 0.f, 0.f, 0.f};

  const int r15 = lane & 15;
  const int s0 = (lane >> 4) ^ (lane & 7);
  const uint16_t* Ard0 = &As[(wm * 64 + r15) * 64 + s0 * 8];
  const uint16_t* Ard1 = &As[(wm * 64 + r15) * 64 + (s0 ^ 4) * 8];
  const uint16_t* Brd0 = &Bs[(wn * 64 + r15) * 64 + s0 * 8];
  const uint16_t* Brd1 = &Bs[(wn * 64 + r15) * 64 + (s0 ^ 4) * 8];

#pragma unroll
  for (int kt = 0; kt < F_DIM / 64; ++kt) {
    __syncthreads();
#pragma unroll
    for (int j = 0; j < 4; ++j) gld_lds16(agp[j] + kt * 64, alds[j]);
#pragma unroll
    for (int j = 0; j < 4; ++j) gld_lds16(bgp[j] + kt * 64, blds[j]);
    __syncthreads();

#pragma unroll
    for (int h = 0; h < 2; ++h) {
      const uint16_t* Ard = h ? Ard1 : Ard0;
      const uint16_t* Brd = h ? Brd1 : Brd0;
      bf16x8 af[4], bfv[4];
#pragma unroll
      for (int mi = 0; mi < 4; ++mi) af[mi] = *(const bf16x8*)(Ard + mi * 16 * 64);
#pragma unroll
      for (int ni = 0; ni < 4; ++ni) bfv[ni] = *(const bf16x8*)(Brd + ni * 16 * 64);
#pragma unroll
      for (int mi = 0; mi < 4; ++mi)
#pragma unroll
        for (int ni = 0; ni < 4; ++ni)
          acc[mi][ni] = __builtin_amdgcn_mfma_f32_16x16x32_bf16(af[mi], bfv[ni], acc[mi][ni], 0, 0, 0);
    }
  }

  float bias4[4]; int d4a[4];
#pragma unroll
  for (int ni = 0; ni < 4; ++ni) {
    d4a[ni] = c0 + wn * 64 + ni * 16 + r15;
    bias4[ni] = b2[(size_t)e * D_DIM + d4a[ni]];
  }
  const int rq = (lane >> 4) * 4;
#pragma unroll
  for (int mi = 0; mi < 4; ++mi)
#pragma unroll
    for (int r = 0; r < 4; ++r) {
      int grow = row0 + wm * 64 + mi * 16 + rq + r;
      if (grow >= n_e) continue;
      size_t yb = (size_t)(base + grow) * D_DIM;
#pragma unroll
      for (int ni = 0; ni < 4; ++ni)
        y[yb + d4a[ni]] = acc[mi][ni][r] + bias4[ni];
    }
}

// ---------------- K8: combine the two expert outputs per token ----------------
__global__ __launch_bounds__(256) void combine_kernel(
    const float* __restrict__ y, const int* __restrict__ pos_of,
    const float* __restrict__ wts, float* __restrict__ out) {
  int t = blockIdx.x;
  int d4 = threadIdx.x * 4;
  int p0 = pos_of[t * 2], p1 = pos_of[t * 2 + 1];
  float w0 = wts[t * 2], w1v = wts[t * 2 + 1];
  float4 a = *(const float4*)&y[(size_t)p0 * D_DIM + d4];
  float4 b = *(const float4*)&y[(size_t)p1 * D_DIM + d4];
  float4 o;
  o.x = w0 * a.x + w1v * b.x;
  o.y = w0 * a.y + w1v * b.y;
  o.z = w0 * a.z + w1v * b.z;
  o.w = w0 * a.w + w1v * b.w;
  *(float4*)&out[(size_t)t * D_DIM + d4] = o;
}

extern "C" void kernel_launch(void* const* d_in, const int* in_sizes, int n_in,
                              void* d_out, int out_size, void* d_ws, size_t ws_size,
                              hipStream_t stream) {
  const float* x      = (const float*)d_in[0];
  const float* gate_w = (const float*)d_in[1];
  const float* w1     = (const float*)d_in[2];
  const float* b1     = (const float*)d_in[3];
  const float* w2     = (const float*)d_in[4];
  const float* b2     = (const float*)d_in[5];
  float* out = (float*)d_out;

  char* ws = (char*)d_ws;
  int*      offsets = (int*)(ws + OFF_OFFSETS);
  int*      sel     = (int*)(ws + OFF_SEL);
  float*    wts     = (float*)(ws + OFF_WTS);
  int*      pos_of  = (int*)(ws + OFF_POSOF);
  uint16_t* f_act   = (uint16_t*)(ws + OFF_FACT);
  uint16_t* xg      = (uint16_t*)(ws + OFF_XG);
  uint16_t* w1b     = (uint16_t*)(ws + OFF_WB);
  float*    yb      = (float*)(ws + OFF_Y);       // overlays w1b tail (w1b dead by gemm2)

  const bool fused = ws_size >= WS_NEED_FUSED;
  uint16_t* w2b = fused ? (uint16_t*)(ws + OFF_W2B2)
                        : (uint16_t*)(ws + OFF_WB);   // fallback: reuse w1b region after gemm1

  cvt_w1_kernel<<<E_NUM * C2F, 256, 0, stream>>>(w1, w1b);
  gate_route_kernel<<<T_TOK, 256, 0, stream>>>(x, gate_w, sel, wts);
  route_scan_kernel<<<1, 256, 0, stream>>>(sel, pos_of, offsets);
  gather_x_kernel<<<T_TOK, 256, 0, stream>>>(x, pos_of, xg);

  if (fused) {
    // z == E_NUM slice converts w2 -> w2b concurrently with the GEMM blocks
    gemm1_kernel<<<dim3(C2F / 128, 64, E_NUM + 1), 256, 0, stream>>>(
        xg, w1b, b1, offsets, f_act, w2, w2b);
  } else {
    gemm1_kernel<<<dim3(C2F / 128, 64, E_NUM), 256, 0, stream>>>(
        xg, w1b, b1, offsets, f_act, w2, w2b);
    cvt_bf16_kernel<<<(E_NUM * D_DIM * F_DIM / 4) / 256, 256, 0, stream>>>(
        w2, w2b, E_NUM * D_DIM * F_DIM / 4);
  }

  gemm2_kernel<<<dim3(D_DIM / 128, 64, E_NUM), 256, 0, stream>>>(f_act, w2b, b2, offsets, yb);
  combine_kernel<<<T_TOK, 256, 0, stream>>>(yb, pos_of, wts, out);
}